// Round 1
// baseline (1719.514 us; speedup 1.0000x reference)
//
#include <hip/hip_runtime.h>
#include <math.h>

// Problem constants (from reference)
#define HID 64      // H*C
#define NH 4
#define NC 16
#define EDIM 16
#define OUTD 128
#define NEG 0.2f

// ---------------- CSR build ----------------

__global__ void hist_kernel(const int* __restrict__ dst, int* __restrict__ deg, int E) {
    int e = blockIdx.x * 256 + threadIdx.x;
    if (e < E) atomicAdd(&deg[dst[e]], 1);
}

__global__ void scan_a(const int* __restrict__ deg, int* __restrict__ offs,
                       int* __restrict__ bsum, int n) {
    __shared__ int tmp[1024];
    int i = blockIdx.x * 1024 + threadIdx.x;
    int v = (i < n) ? deg[i] : 0;
    tmp[threadIdx.x] = v;
    __syncthreads();
    for (int off = 1; off < 1024; off <<= 1) {
        int t = (threadIdx.x >= off) ? tmp[threadIdx.x - off] : 0;
        __syncthreads();
        tmp[threadIdx.x] += t;
        __syncthreads();
    }
    if (i < n) offs[i] = tmp[threadIdx.x] - v;   // exclusive
    if (threadIdx.x == 1023) bsum[blockIdx.x] = tmp[1023];
}

__global__ void scan_b(int* __restrict__ bsum, int* __restrict__ offs, int nb, int n) {
    __shared__ int tmp[1024];
    int v = (threadIdx.x < nb) ? bsum[threadIdx.x] : 0;
    tmp[threadIdx.x] = v;
    __syncthreads();
    for (int off = 1; off < 1024; off <<= 1) {
        int t = (threadIdx.x >= off) ? tmp[threadIdx.x - off] : 0;
        __syncthreads();
        tmp[threadIdx.x] += t;
        __syncthreads();
    }
    if (threadIdx.x < nb) bsum[threadIdx.x] = tmp[threadIdx.x] - v;  // exclusive
    if (threadIdx.x == 1023) offs[n] = tmp[1023];                    // total = E
}

__global__ void scan_c(int* __restrict__ offs, const int* __restrict__ bsum, int n) {
    int i = blockIdx.x * 1024 + threadIdx.x;
    if (i < n) offs[i] += bsum[blockIdx.x];
}

__global__ void scatter_kernel(const int* __restrict__ src, const int* __restrict__ dst,
                               const int* __restrict__ offs, int* __restrict__ cursor,
                               int* __restrict__ csr_src, int* __restrict__ csr_eid, int E) {
    int e = blockIdx.x * 256 + threadIdx.x;
    if (e >= E) return;
    int d = dst[e];
    int p = offs[d] + atomicAdd(&cursor[d], 1);
    csr_src[p] = src[e];
    csr_eid[p] = e;
}

// self-loop attr = mean of incoming edge attrs (0 if no in-edges)
__global__ void loopattr_kernel(const int* __restrict__ offs, const int* __restrict__ csr_eid,
                                const float* __restrict__ ea, float* __restrict__ la, int n) {
    int idx = blockIdx.x * 256 + threadIdx.x;
    if (idx >= n * EDIM) return;
    int nd = idx >> 4, k = idx & 15;
    int e0 = offs[nd], e1 = offs[nd + 1];
    float s = 0.f;
    for (int j = e0; j < e1; j++) s += ea[csr_eid[j] * EDIM + k];
    la[idx] = s / fmaxf((float)(e1 - e0), 1.0f);
}

// ---------------- dual GEMM: xl = x@Wl+bl, xr = x@Wr+br ----------------
// x: [n,64], Wl/Wr: [64,64] (k-major rows), out xl/xr: [n,64]

__global__ __launch_bounds__(256)
void dualgemm_kernel(const float* __restrict__ x,
                     const float* __restrict__ Wl, const float* __restrict__ bl,
                     const float* __restrict__ Wr, const float* __restrict__ br,
                     float* __restrict__ xl, float* __restrict__ xr, int n) {
    __shared__ float xs[64 * 65];     // [row][k], pad 65
    __shared__ float ws[64 * 128];    // [k][j]: j<64 -> Wl col, j>=64 -> Wr col
    int tid = threadIdx.x;
    int r0 = blockIdx.x * 64;

#pragma unroll
    for (int t = 0; t < 32; t++) {
        int idx = t * 256 + tid;              // 0..8191
        int k = idx >> 7, j = idx & 127;
        ws[idx] = (j < 64) ? Wl[k * 64 + j] : Wr[k * 64 + (j - 64)];
    }
#pragma unroll
    for (int t = 0; t < 16; t++) {
        int idx = t * 256 + tid;              // 0..4095
        int r = idx >> 6, c = idx & 63;
        float v = (r0 + r < n) ? x[(r0 + r) * 64 + c] : 0.f;
        xs[r * 65 + c] = v;
    }
    __syncthreads();

    int cg = tid & 31;   // 32 col-groups x 4 cols = 128 cols (xl|xr)
    int rg = tid >> 5;   // 8 row-groups x 8 rows

    float acc[8][4];
#pragma unroll
    for (int u = 0; u < 8; u++)
#pragma unroll
        for (int v = 0; v < 4; v++) acc[u][v] = 0.f;

    for (int k = 0; k < 64; k++) {
        float4 wv = *(const float4*)&ws[k * 128 + cg * 4];
        float xv[8];
#pragma unroll
        for (int u = 0; u < 8; u++) xv[u] = xs[(rg * 8 + u) * 65 + k];
#pragma unroll
        for (int u = 0; u < 8; u++) {
            acc[u][0] += xv[u] * wv.x;
            acc[u][1] += xv[u] * wv.y;
            acc[u][2] += xv[u] * wv.z;
            acc[u][3] += xv[u] * wv.w;
        }
    }

    int j0 = cg * 4;
    bool isL = (j0 < 64);
    const float* bp = isL ? bl : br;
    float* op = isL ? xl : xr;
    int jj = isL ? j0 : (j0 - 64);
    float4 bv = *(const float4*)&bp[jj];
#pragma unroll
    for (int u = 0; u < 8; u++) {
        int r = r0 + rg * 8 + u;
        if (r < n) {
            float4 o;
            o.x = acc[u][0] + bv.x; o.y = acc[u][1] + bv.y;
            o.z = acc[u][2] + bv.z; o.w = acc[u][3] + bv.w;
            *(float4*)&op[r * 64 + jj] = o;
        }
    }
}

// ---------------- GATv2 layer: one wave per dst node, online softmax ----------------
// lane = h*16 + c  (matches reshape(-1,H,C) flattening)

__global__ __launch_bounds__(256)
void gat_kernel(const int* __restrict__ offs, const int* __restrict__ csr_src,
                const int* __restrict__ csr_eid, const float* __restrict__ ea,
                const float* __restrict__ la,
                const float* __restrict__ xl, const float* __restrict__ xr,
                const float* __restrict__ We, const float* __restrict__ att,
                const float* __restrict__ bias, float* __restrict__ out, int n) {
    int lane = threadIdx.x & 63;
    int node = blockIdx.x * 4 + (threadIdx.x >> 6);
    node = __builtin_amdgcn_readfirstlane(node);
    if (node >= n) return;

    float wec[16];                 // We column 'lane' in registers
#pragma unroll
    for (int k = 0; k < 16; k++) wec[k] = We[k * 64 + lane];
    float attl = att[lane];
    float xrl = xr[node * 64 + lane];

    float M = -1e30f, S = 0.f, acc = 0.f;
    int e0 = __builtin_amdgcn_readfirstlane(offs[node]);
    int e1 = __builtin_amdgcn_readfirstlane(offs[node + 1]);

    // i = e0-1 is the self-loop; then CSR in-edges
    for (int i = e0 - 1; i < e1; i++) {
        int src;
        const float4* ap;
        if (i < e0) {
            src = node;
            ap = (const float4*)(la + (size_t)node * EDIM);
        } else {
            src = __builtin_amdgcn_readfirstlane(csr_src[i]);
            int eid = __builtin_amdgcn_readfirstlane(csr_eid[i]);
            ap = (const float4*)(ea + (size_t)eid * EDIM);
        }
        float xls = xl[src * 64 + lane];
        float4 a0 = ap[0], a1 = ap[1], a2 = ap[2], a3 = ap[3];
        float e = a0.x * wec[0] + a0.y * wec[1] + a0.z * wec[2] + a0.w * wec[3]
                + a1.x * wec[4] + a1.y * wec[5] + a1.z * wec[6] + a1.w * wec[7]
                + a2.x * wec[8] + a2.y * wec[9] + a2.z * wec[10] + a2.w * wec[11]
                + a3.x * wec[12] + a3.y * wec[13] + a3.z * wec[14] + a3.w * wec[15];
        float m = xls + xrl + e;
        m = fmaxf(m, NEG * m);          // leaky_relu (slope<1)
        float sp = m * attl;
        sp += __shfl_xor(sp, 1);        // reduce over c within 16-lane head
        sp += __shfl_xor(sp, 2);
        sp += __shfl_xor(sp, 4);
        sp += __shfl_xor(sp, 8);
        float Mn = fmaxf(M, sp);
        float fs = __expf(M - Mn);
        float z = __expf(sp - Mn);
        S = S * fs + z;
        acc = acc * fs + z * xls;
        M = Mn;
    }
    out[node * 64 + lane] = fmaxf(acc / S + bias[lane], 0.f);
}

// ---------------- pooling + MLP ----------------

__global__ void pool_kernel(const float* __restrict__ x, const int* __restrict__ batch,
                            float* __restrict__ gsum, float* __restrict__ gcnt, int n) {
    int idx = blockIdx.x * 256 + threadIdx.x;
    if (idx >= n * 64) return;
    int nd = idx >> 6, c = idx & 63;
    int b = batch[nd];
    atomicAdd(&gsum[b * 64 + c], x[idx]);
    if (c == 0) atomicAdd(&gcnt[b], 1.0f);
}

__global__ __launch_bounds__(128)
void mlp_kernel(const float* __restrict__ gsum, const float* __restrict__ gcnt,
                const float* __restrict__ W1, const float* __restrict__ b1,
                const float* __restrict__ W2, const float* __restrict__ b2,
                float* __restrict__ out) {
    __shared__ float gv[64];
    __shared__ float hid[128];
    int g = blockIdx.x, j = threadIdx.x;
    if (j < 64) gv[j] = gsum[g * 64 + j] / fmaxf(gcnt[g], 1.0f);
    __syncthreads();
    float h = b1[j];
    for (int k = 0; k < 64; k++) h += gv[k] * W1[k * 128 + j];
    hid[j] = fmaxf(h, 0.f);
    __syncthreads();
    float o = b2[j];
    for (int k = 0; k < 128; k++) o += hid[k] * W2[k * 128 + j];
    out[g * 128 + j] = o;
}

// ---------------- launch ----------------

extern "C" void kernel_launch(void* const* d_in, const int* in_sizes, int n_in,
                              void* d_out, int out_size, void* d_ws, size_t ws_size,
                              hipStream_t stream) {
    const float* nf   = (const float*)d_in[0];
    const int*   ei   = (const int*)d_in[1];      // [2,E]: row0=src, row1=dst
    const float* eaw  = (const float*)d_in[2];    // [E,16]
    const int*   bat  = (const int*)d_in[3];
    const float* l0_Wl = (const float*)d_in[4];
    const float* l0_bl = (const float*)d_in[5];
    const float* l0_Wr = (const float*)d_in[6];
    const float* l0_br = (const float*)d_in[7];
    const float* l0_We = (const float*)d_in[8];
    const float* l0_att = (const float*)d_in[9];
    const float* l0_bias = (const float*)d_in[10];
    const float* l1_Wl = (const float*)d_in[11];
    const float* l1_bl = (const float*)d_in[12];
    const float* l1_Wr = (const float*)d_in[13];
    const float* l1_br = (const float*)d_in[14];
    const float* l1_We = (const float*)d_in[15];
    const float* l1_att = (const float*)d_in[16];
    const float* l1_bias = (const float*)d_in[17];
    const float* mW1 = (const float*)d_in[18];
    const float* mb1 = (const float*)d_in[19];
    const float* mW2 = (const float*)d_in[20];
    const float* mb2 = (const float*)d_in[21];

    const int N = in_sizes[0] / 64;
    const int E = in_sizes[1] / 2;
    const int G = out_size / OUTD;

    // workspace carve-up (256B aligned)
    char* w = (char*)d_ws;
    auto carve = [&](size_t bytes) {
        void* p = (void*)w;
        w += (bytes + 255) & ~(size_t)255;
        return p;
    };
    int*   deg     = (int*)carve((size_t)N * 4);
    int*   offs    = (int*)carve((size_t)(N + 1) * 4);
    int*   cursor  = (int*)carve((size_t)N * 4);
    int*   bsum    = (int*)carve(4096 * 4);
    int*   csr_src = (int*)carve((size_t)E * 4);
    int*   csr_eid = (int*)carve((size_t)E * 4);
    float* la      = (float*)carve((size_t)N * EDIM * 4);
    float* xl      = (float*)carve((size_t)N * 64 * 4);
    float* xr      = (float*)carve((size_t)N * 64 * 4);
    float* x1      = (float*)carve((size_t)N * 64 * 4);
    float* x2      = (float*)carve((size_t)N * 64 * 4);
    float* gsum    = (float*)carve((size_t)G * 64 * 4);
    float* gcnt    = (float*)carve((size_t)G * 4);

    hipMemsetAsync(deg, 0, (size_t)N * 4, stream);
    hipMemsetAsync(cursor, 0, (size_t)N * 4, stream);
    hipMemsetAsync(gsum, 0, (size_t)G * 64 * 4, stream);
    hipMemsetAsync(gcnt, 0, (size_t)G * 4, stream);

    const int* src = ei;
    const int* dst = ei + E;

    hist_kernel<<<(E + 255) / 256, 256, 0, stream>>>(dst, deg, E);

    int nb = (N + 1023) / 1024;
    scan_a<<<nb, 1024, 0, stream>>>(deg, offs, bsum, N);
    scan_b<<<1, 1024, 0, stream>>>(bsum, offs, nb, N);
    scan_c<<<nb, 1024, 0, stream>>>(offs, bsum, N);

    scatter_kernel<<<(E + 255) / 256, 256, 0, stream>>>(src, dst, offs, cursor,
                                                        csr_src, csr_eid, E);
    loopattr_kernel<<<(N * EDIM + 255) / 256, 256, 0, stream>>>(offs, csr_eid, eaw, la, N);

    // layer 0
    dualgemm_kernel<<<(N + 63) / 64, 256, 0, stream>>>(nf, l0_Wl, l0_bl, l0_Wr, l0_br,
                                                       xl, xr, N);
    gat_kernel<<<(N + 3) / 4, 256, 0, stream>>>(offs, csr_src, csr_eid, eaw, la,
                                                xl, xr, l0_We, l0_att, l0_bias, x1, N);
    // layer 1
    dualgemm_kernel<<<(N + 63) / 64, 256, 0, stream>>>(x1, l1_Wl, l1_bl, l1_Wr, l1_br,
                                                       xl, xr, N);
    gat_kernel<<<(N + 3) / 4, 256, 0, stream>>>(offs, csr_src, csr_eid, eaw, la,
                                                xl, xr, l1_We, l1_att, l1_bias, x2, N);

    // pool + MLP
    pool_kernel<<<(N * 64 + 255) / 256, 256, 0, stream>>>(x2, bat, gsum, gcnt, N);
    mlp_kernel<<<G, 128, 0, stream>>>(gsum, gcnt, mW1, mb1, mW2, mb2, (float*)d_out);
}

// Round 2
// 995.600 us; speedup vs baseline: 1.7271x; 1.7271x over previous
//
#include <hip/hip_runtime.h>
#include <math.h>

// Problem constants (from reference)
#define HID 64      // H*C
#define NH 4
#define NC 16
#define EDIM 16
#define OUTD 128
#define NEG 0.2f

// ---------------- CSR build ----------------

__global__ void hist_kernel(const int* __restrict__ dst, int* __restrict__ deg, int E) {
    int e = blockIdx.x * 256 + threadIdx.x;
    if (e < E) atomicAdd(&deg[dst[e]], 1);
}

__global__ void scan_a(const int* __restrict__ deg, int* __restrict__ offs,
                       int* __restrict__ bsum, int n) {
    __shared__ int tmp[1024];
    int i = blockIdx.x * 1024 + threadIdx.x;
    int v = (i < n) ? deg[i] : 0;
    tmp[threadIdx.x] = v;
    __syncthreads();
    for (int off = 1; off < 1024; off <<= 1) {
        int t = (threadIdx.x >= off) ? tmp[threadIdx.x - off] : 0;
        __syncthreads();
        tmp[threadIdx.x] += t;
        __syncthreads();
    }
    if (i < n) offs[i] = tmp[threadIdx.x] - v;   // exclusive
    if (threadIdx.x == 1023) bsum[blockIdx.x] = tmp[1023];
}

__global__ void scan_b(int* __restrict__ bsum, int* __restrict__ offs, int nb, int n) {
    __shared__ int tmp[1024];
    int v = (threadIdx.x < nb) ? bsum[threadIdx.x] : 0;
    tmp[threadIdx.x] = v;
    __syncthreads();
    for (int off = 1; off < 1024; off <<= 1) {
        int t = (threadIdx.x >= off) ? tmp[threadIdx.x - off] : 0;
        __syncthreads();
        tmp[threadIdx.x] += t;
        __syncthreads();
    }
    if (threadIdx.x < nb) bsum[threadIdx.x] = tmp[threadIdx.x] - v;  // exclusive
    if (threadIdx.x == 1023) offs[n] = tmp[1023];                    // total = E
}

__global__ void scan_c(int* __restrict__ offs, const int* __restrict__ bsum, int n) {
    int i = blockIdx.x * 1024 + threadIdx.x;
    if (i < n) offs[i] += bsum[blockIdx.x];
}

__global__ void scatter_kernel(const int* __restrict__ src, const int* __restrict__ dst,
                               const int* __restrict__ offs, int* __restrict__ cursor,
                               int* __restrict__ csr_src, int* __restrict__ csr_eid, int E) {
    int e = blockIdx.x * 256 + threadIdx.x;
    if (e >= E) return;
    int d = dst[e];
    int p = offs[d] + atomicAdd(&cursor[d], 1);
    csr_src[p] = src[e];
    csr_eid[p] = e;
}

// self-loop attr = mean of incoming edge attrs (0 if no in-edges)
__global__ void loopattr_kernel(const int* __restrict__ offs, const int* __restrict__ csr_eid,
                                const float* __restrict__ ea, float* __restrict__ la, int n) {
    int idx = blockIdx.x * 256 + threadIdx.x;
    if (idx >= n * EDIM) return;
    int nd = idx >> 4, k = idx & 15;
    int e0 = offs[nd], e1 = offs[nd + 1];
    float s = 0.f;
    for (int j = e0; j < e1; j++) s += ea[csr_eid[j] * EDIM + k];
    la[idx] = s / fmaxf((float)(e1 - e0), 1.0f);
}

// ---------------- dual GEMM: xl = x@Wl+bl, xr = x@Wr+br ----------------
// x: [n,64], Wl/Wr: [64,64] (k-major rows), out xl/xr: [n,64]

__global__ __launch_bounds__(256)
void dualgemm_kernel(const float* __restrict__ x,
                     const float* __restrict__ Wl, const float* __restrict__ bl,
                     const float* __restrict__ Wr, const float* __restrict__ br,
                     float* __restrict__ xl, float* __restrict__ xr, int n) {
    __shared__ float xs[64 * 65];     // [row][k], pad 65
    __shared__ float ws[64 * 128];    // [k][j]: j<64 -> Wl col, j>=64 -> Wr col
    int tid = threadIdx.x;
    int r0 = blockIdx.x * 64;

#pragma unroll
    for (int t = 0; t < 32; t++) {
        int idx = t * 256 + tid;              // 0..8191
        int k = idx >> 7, j = idx & 127;
        ws[idx] = (j < 64) ? Wl[k * 64 + j] : Wr[k * 64 + (j - 64)];
    }
#pragma unroll
    for (int t = 0; t < 16; t++) {
        int idx = t * 256 + tid;              // 0..4095
        int r = idx >> 6, c = idx & 63;
        float v = (r0 + r < n) ? x[(r0 + r) * 64 + c] : 0.f;
        xs[r * 65 + c] = v;
    }
    __syncthreads();

    int cg = tid & 31;   // 32 col-groups x 4 cols = 128 cols (xl|xr)
    int rg = tid >> 5;   // 8 row-groups x 8 rows

    float acc[8][4];
#pragma unroll
    for (int u = 0; u < 8; u++)
#pragma unroll
        for (int v = 0; v < 4; v++) acc[u][v] = 0.f;

    for (int k = 0; k < 64; k++) {
        float4 wv = *(const float4*)&ws[k * 128 + cg * 4];
        float xv[8];
#pragma unroll
        for (int u = 0; u < 8; u++) xv[u] = xs[(rg * 8 + u) * 65 + k];
#pragma unroll
        for (int u = 0; u < 8; u++) {
            acc[u][0] += xv[u] * wv.x;
            acc[u][1] += xv[u] * wv.y;
            acc[u][2] += xv[u] * wv.z;
            acc[u][3] += xv[u] * wv.w;
        }
    }

    int j0 = cg * 4;
    bool isL = (j0 < 64);
    const float* bp = isL ? bl : br;
    float* op = isL ? xl : xr;
    int jj = isL ? j0 : (j0 - 64);
    float4 bv = *(const float4*)&bp[jj];
#pragma unroll
    for (int u = 0; u < 8; u++) {
        int r = r0 + rg * 8 + u;
        if (r < n) {
            float4 o;
            o.x = acc[u][0] + bv.x; o.y = acc[u][1] + bv.y;
            o.z = acc[u][2] + bv.z; o.w = acc[u][3] + bv.w;
            *(float4*)&op[r * 64 + jj] = o;
        }
    }
}

// ---------------- GATv2 layer: one wave per dst node, online softmax ----------------
// lane = h*16 + c  (matches reshape(-1,H,C) flattening)

__global__ __launch_bounds__(256)
void gat_kernel(const int* __restrict__ offs, const int* __restrict__ csr_src,
                const int* __restrict__ csr_eid, const float* __restrict__ ea,
                const float* __restrict__ la,
                const float* __restrict__ xl, const float* __restrict__ xr,
                const float* __restrict__ We, const float* __restrict__ att,
                const float* __restrict__ bias, float* __restrict__ out, int n) {
    int lane = threadIdx.x & 63;
    int node = blockIdx.x * 4 + (threadIdx.x >> 6);
    node = __builtin_amdgcn_readfirstlane(node);
    if (node >= n) return;

    float wec[16];                 // We column 'lane' in registers
#pragma unroll
    for (int k = 0; k < 16; k++) wec[k] = We[k * 64 + lane];
    float attl = att[lane];
    float xrl = xr[node * 64 + lane];

    float M = -1e30f, S = 0.f, acc = 0.f;
    int e0 = __builtin_amdgcn_readfirstlane(offs[node]);
    int e1 = __builtin_amdgcn_readfirstlane(offs[node + 1]);

    // i = e0-1 is the self-loop; then CSR in-edges
    for (int i = e0 - 1; i < e1; i++) {
        int src;
        const float4* ap;
        if (i < e0) {
            src = node;
            ap = (const float4*)(la + (size_t)node * EDIM);
        } else {
            src = __builtin_amdgcn_readfirstlane(csr_src[i]);
            int eid = __builtin_amdgcn_readfirstlane(csr_eid[i]);
            ap = (const float4*)(ea + (size_t)eid * EDIM);
        }
        float xls = xl[src * 64 + lane];
        float4 a0 = ap[0], a1 = ap[1], a2 = ap[2], a3 = ap[3];
        float e = a0.x * wec[0] + a0.y * wec[1] + a0.z * wec[2] + a0.w * wec[3]
                + a1.x * wec[4] + a1.y * wec[5] + a1.z * wec[6] + a1.w * wec[7]
                + a2.x * wec[8] + a2.y * wec[9] + a2.z * wec[10] + a2.w * wec[11]
                + a3.x * wec[12] + a3.y * wec[13] + a3.z * wec[14] + a3.w * wec[15];
        float m = xls + xrl + e;
        m = fmaxf(m, NEG * m);          // leaky_relu (slope<1)
        float sp = m * attl;
        sp += __shfl_xor(sp, 1);        // reduce over c within 16-lane head
        sp += __shfl_xor(sp, 2);
        sp += __shfl_xor(sp, 4);
        sp += __shfl_xor(sp, 8);
        float Mn = fmaxf(M, sp);
        float fs = __expf(M - Mn);
        float z = __expf(sp - Mn);
        S = S * fs + z;
        acc = acc * fs + z * xls;
        M = Mn;
    }
    out[node * 64 + lane] = fmaxf(acc / S + bias[lane], 0.f);
}

// ---------------- fused pool (batch is sorted) + MLP: one block per graph ----------------

__global__ __launch_bounds__(256)
void pool_mlp_kernel(const float* __restrict__ x, const int* __restrict__ batch, int n,
                     const float* __restrict__ W1, const float* __restrict__ b1,
                     const float* __restrict__ W2, const float* __restrict__ b2,
                     float* __restrict__ out) {
    __shared__ float psum[4][64];
    __shared__ float gv[64];
    __shared__ float hid[128];
    __shared__ int bounds[2];

    int g = blockIdx.x;
    int tid = threadIdx.x;
    int wave = tid >> 6, lane = tid & 63;

    if (tid < 2) {
        // lower_bound(batch, g + tid): first index with batch[i] >= g+tid
        int target = g + tid;
        int lo = 0, hi = n;
        while (lo < hi) {
            int mid = (lo + hi) >> 1;
            if (batch[mid] < target) lo = mid + 1; else hi = mid;
        }
        bounds[tid] = lo;
    }
    __syncthreads();
    int lo = bounds[0], hi = bounds[1];
    int cnt = hi - lo;

    // each wave sums channel 'lane' over nodes lo+wave, step 4
    float s = 0.f;
    for (int nd = lo + wave; nd < hi; nd += 4)
        s += x[(size_t)nd * 64 + lane];
    psum[wave][lane] = s;
    __syncthreads();

    if (tid < 64)
        gv[tid] = (psum[0][tid] + psum[1][tid] + psum[2][tid] + psum[3][tid])
                  / fmaxf((float)cnt, 1.0f);
    __syncthreads();

    if (tid < 128) {
        float h = b1[tid];
        for (int k = 0; k < 64; k++) h += gv[k] * W1[k * 128 + tid];
        hid[tid] = fmaxf(h, 0.f);
    }
    __syncthreads();
    if (tid < 128) {
        float o = b2[tid];
        for (int k = 0; k < 128; k++) o += hid[k] * W2[k * 128 + tid];
        out[g * 128 + tid] = o;
    }
}

// ---------------- launch ----------------

extern "C" void kernel_launch(void* const* d_in, const int* in_sizes, int n_in,
                              void* d_out, int out_size, void* d_ws, size_t ws_size,
                              hipStream_t stream) {
    const float* nf   = (const float*)d_in[0];
    const int*   ei   = (const int*)d_in[1];      // [2,E]: row0=src, row1=dst
    const float* eaw  = (const float*)d_in[2];    // [E,16]
    const int*   bat  = (const int*)d_in[3];
    const float* l0_Wl = (const float*)d_in[4];
    const float* l0_bl = (const float*)d_in[5];
    const float* l0_Wr = (const float*)d_in[6];
    const float* l0_br = (const float*)d_in[7];
    const float* l0_We = (const float*)d_in[8];
    const float* l0_att = (const float*)d_in[9];
    const float* l0_bias = (const float*)d_in[10];
    const float* l1_Wl = (const float*)d_in[11];
    const float* l1_bl = (const float*)d_in[12];
    const float* l1_Wr = (const float*)d_in[13];
    const float* l1_br = (const float*)d_in[14];
    const float* l1_We = (const float*)d_in[15];
    const float* l1_att = (const float*)d_in[16];
    const float* l1_bias = (const float*)d_in[17];
    const float* mW1 = (const float*)d_in[18];
    const float* mb1 = (const float*)d_in[19];
    const float* mW2 = (const float*)d_in[20];
    const float* mb2 = (const float*)d_in[21];

    const int N = in_sizes[0] / 64;
    const int E = in_sizes[1] / 2;
    const int G = out_size / OUTD;

    // workspace carve-up (256B aligned)
    char* w = (char*)d_ws;
    auto carve = [&](size_t bytes) {
        void* p = (void*)w;
        w += (bytes + 255) & ~(size_t)255;
        return p;
    };
    int*   deg     = (int*)carve((size_t)N * 4);
    int*   offs    = (int*)carve((size_t)(N + 1) * 4);
    int*   cursor  = (int*)carve((size_t)N * 4);
    int*   bsum    = (int*)carve(4096 * 4);
    int*   csr_src = (int*)carve((size_t)E * 4);
    int*   csr_eid = (int*)carve((size_t)E * 4);
    float* la      = (float*)carve((size_t)N * EDIM * 4);
    float* xl      = (float*)carve((size_t)N * 64 * 4);
    float* xr      = (float*)carve((size_t)N * 64 * 4);
    float* x1      = (float*)carve((size_t)N * 64 * 4);
    float* x2      = (float*)carve((size_t)N * 64 * 4);

    hipMemsetAsync(deg, 0, (size_t)N * 4, stream);
    hipMemsetAsync(cursor, 0, (size_t)N * 4, stream);

    const int* src = ei;
    const int* dst = ei + E;

    hist_kernel<<<(E + 255) / 256, 256, 0, stream>>>(dst, deg, E);

    int nb = (N + 1023) / 1024;
    scan_a<<<nb, 1024, 0, stream>>>(deg, offs, bsum, N);
    scan_b<<<1, 1024, 0, stream>>>(bsum, offs, nb, N);
    scan_c<<<nb, 1024, 0, stream>>>(offs, bsum, N);

    scatter_kernel<<<(E + 255) / 256, 256, 0, stream>>>(src, dst, offs, cursor,
                                                        csr_src, csr_eid, E);
    loopattr_kernel<<<(N * EDIM + 255) / 256, 256, 0, stream>>>(offs, csr_eid, eaw, la, N);

    // layer 0
    dualgemm_kernel<<<(N + 63) / 64, 256, 0, stream>>>(nf, l0_Wl, l0_bl, l0_Wr, l0_br,
                                                       xl, xr, N);
    gat_kernel<<<(N + 3) / 4, 256, 0, stream>>>(offs, csr_src, csr_eid, eaw, la,
                                                xl, xr, l0_We, l0_att, l0_bias, x1, N);
    // layer 1
    dualgemm_kernel<<<(N + 63) / 64, 256, 0, stream>>>(x1, l1_Wl, l1_bl, l1_Wr, l1_br,
                                                       xl, xr, N);
    gat_kernel<<<(N + 3) / 4, 256, 0, stream>>>(offs, csr_src, csr_eid, eaw, la,
                                                xl, xr, l1_We, l1_att, l1_bias, x2, N);

    // fused pool + MLP (one block per graph; batch sorted)
    pool_mlp_kernel<<<G, 256, 0, stream>>>(x2, bat, N, mW1, mb1, mW2, mb2, (float*)d_out);
}